// Round 14
// baseline (181.262 us; speedup 1.0000x reference)
//
#include <hip/hip_runtime.h>
#include <hip/hip_bf16.h>
#include <cstdint>
#include <cstddef>

typedef __attribute__((ext_vector_type(8))) short bf16x8;   // 8 bf16 in 4 VGPRs
typedef __attribute__((ext_vector_type(4))) float f32x4;
typedef __attribute__((ext_vector_type(4))) unsigned short us4;

// Native bf16 convert (RNE) — compiler emits v_cvt_pk_bf16_f32 for pairs.
static __device__ __forceinline__ unsigned short f2bf(float f) {
    __hip_bfloat16 h = __float2bfloat16(f);
    return *reinterpret_cast<unsigned short*>(&h);
}

static __device__ __forceinline__ f32x4 mfma_bf16(bf16x8 a, bf16x8 b, f32x4 c) {
    return __builtin_amdgcn_mfma_f32_16x16x32_bf16(a, b, c, 0, 0, 0);
}

static __device__ __forceinline__ bf16x8 pack8(float4 a, float4 b) {
    bf16x8 f;
    f[0]=(short)f2bf(a.x); f[1]=(short)f2bf(a.y); f[2]=(short)f2bf(a.z); f[3]=(short)f2bf(a.w);
    f[4]=(short)f2bf(b.x); f[5]=(short)f2bf(b.y); f[6]=(short)f2bf(b.z); f[7]=(short)f2bf(b.w);
    return f;
}

// Branchless exact-erf GELU (A&S 7.1.26, |erf err| < 1.5e-7).
static __device__ __forceinline__ float gelu_erf(float v) {
    float s = v * 0.70710678118654752f;
    float a = fabsf(s);
    float t = __builtin_amdgcn_rcpf(1.0f + 0.3275911f * a);
    float poly = ((((1.061405429f * t - 1.453152027f) * t + 1.421413741f) * t
                   - 0.284496736f) * t + 0.254829592f) * t;
    float e = 1.0f - poly * __expf(-a * a);
    float erfv = copysignf(e, s);
    return 0.5f * v * (1.0f + erfv);
}

// async 16B global -> LDS (linear dest: wave-uniform base + lane*16)
static __device__ __forceinline__ void load_lds16(const unsigned short* g, unsigned short* l) {
    __builtin_amdgcn_global_load_lds(
        (const __attribute__((address_space(1))) unsigned int*)g,
        (__attribute__((address_space(3))) unsigned int*)l, 16, 0, 0);
}

// ---------------------------------------------------------------------------
// Attention (at its HBM floor ~45us): one block per (window, head).
// ---------------------------------------------------------------------------
__global__ __launch_bounds__(256) void attn_kernel(
    const float* __restrict__ q, const float* __restrict__ k,
    const float* __restrict__ v, const float* __restrict__ mask,
    float* __restrict__ xout)
{
    __shared__ unsigned short Qs[64][40];
    __shared__ unsigned short Ks[64][40];
    __shared__ unsigned short Vt[32][72];
    __shared__ unsigned short Ps[64][72];

    const int tid  = threadIdx.x;
    const int b    = blockIdx.x >> 3;
    const int h    = blockIdx.x & 7;
    const int lane = tid & 63;
    const int l15  = lane & 15;
    const int g    = lane >> 4;
    const int w    = tid >> 6;

    {
        int row = tid >> 2;
        int seg = tid & 3;
        size_t base = ((size_t)(b * 64 + row)) * 256 + h * 32 + seg * 8;

        float4 a0 = *(const float4*)(q + base);
        float4 a1 = *(const float4*)(q + base + 4);
        unsigned short* p = &Qs[row][seg * 8];
        p[0]=f2bf(a0.x); p[1]=f2bf(a0.y); p[2]=f2bf(a0.z); p[3]=f2bf(a0.w);
        p[4]=f2bf(a1.x); p[5]=f2bf(a1.y); p[6]=f2bf(a1.z); p[7]=f2bf(a1.w);

        a0 = *(const float4*)(k + base);
        a1 = *(const float4*)(k + base + 4);
        p = &Ks[row][seg * 8];
        p[0]=f2bf(a0.x); p[1]=f2bf(a0.y); p[2]=f2bf(a0.z); p[3]=f2bf(a0.w);
        p[4]=f2bf(a1.x); p[5]=f2bf(a1.y); p[6]=f2bf(a1.z); p[7]=f2bf(a1.w);

        a0 = *(const float4*)(v + base);
        a1 = *(const float4*)(v + base + 4);
        int c = seg * 8;
        Vt[c + 0][row] = f2bf(a0.x);
        Vt[c + 1][row] = f2bf(a0.y);
        Vt[c + 2][row] = f2bf(a0.z);
        Vt[c + 3][row] = f2bf(a0.w);
        Vt[c + 4][row] = f2bf(a1.x);
        Vt[c + 5][row] = f2bf(a1.y);
        Vt[c + 6][row] = f2bf(a1.z);
        Vt[c + 7][row] = f2bf(a1.w);
    }
    __syncthreads();

    f32x4 s[4];
    {
        bf16x8 aQ = *(const bf16x8*)&Qs[w * 16 + l15][g * 8];
        #pragma unroll
        for (int ct = 0; ct < 4; ++ct) {
            bf16x8 bK = *(const bf16x8*)&Ks[ct * 16 + l15][g * 8];
            f32x4 z = {0.f, 0.f, 0.f, 0.f};
            s[ct] = mfma_bf16(aQ, bK, z);
        }
    }

    const float* mbase = mask + (size_t)(b & 63) * 4096;
    const float INV = 0.17677669529663688f;
    float rsum[4];
    #pragma unroll
    for (int r = 0; r < 4; ++r) {
        int row = w * 16 + g * 4 + r;
        float pr[4];
        #pragma unroll
        for (int ct = 0; ct < 4; ++ct)
            pr[ct] = (s[ct][r] + mbase[row * 64 + ct * 16 + l15]) * INV;
        float m = fmaxf(fmaxf(pr[0], pr[1]), fmaxf(pr[2], pr[3]));
        #pragma unroll
        for (int off = 1; off < 16; off <<= 1)
            m = fmaxf(m, __shfl_xor(m, off));
        float sum = 0.f;
        #pragma unroll
        for (int ct = 0; ct < 4; ++ct) { pr[ct] = __expf(pr[ct] - m); sum += pr[ct]; }
        #pragma unroll
        for (int off = 1; off < 16; off <<= 1)
            sum += __shfl_xor(sum, off);
        rsum[r] = sum;
        #pragma unroll
        for (int ct = 0; ct < 4; ++ct)
            Ps[row][ct * 16 + l15] = f2bf(pr[ct]);
    }

    f32x4 o[2] = {};
    #pragma unroll
    for (int ks = 0; ks < 2; ++ks) {
        bf16x8 pa = *(const bf16x8*)&Ps[w * 16 + l15][ks * 32 + g * 8];
        #pragma unroll
        for (int n = 0; n < 2; ++n) {
            bf16x8 vb = *(const bf16x8*)&Vt[n * 16 + l15][ks * 32 + g * 8];
            o[n] = mfma_bf16(pa, vb, o[n]);
        }
    }

    #pragma unroll
    for (int n = 0; n < 2; ++n) {
        #pragma unroll
        for (int r = 0; r < 4; ++r) {
            int row = w * 16 + g * 4 + r;
            xout[((size_t)(b * 64 + row)) * 256 + h * 32 + n * 16 + l15] =
                o[n][r] / rsum[r];
        }
    }
}

// ---------------------------------------------------------------------------
// prep_w1: w1 as sigma-permuted MFMA A-operand; NOW in 8 KB SUB-PANELS of 16
// hidden each: sub-panel s = c*2 + nt at offset s*4096, span ks (0..7) * 512.
// ---------------------------------------------------------------------------
__global__ __launch_bounds__(256) void prep_w1(const float* __restrict__ src,
                                               unsigned short* __restrict__ dst)
{
    __shared__ float tile[64][65];              // [k_local][n_local]
    const int kt = blockIdx.x, nb = blockIdx.y;
    const int t = threadIdx.x;
    const int r0 = t >> 4, c4 = (t & 15) * 4;
    #pragma unroll
    for (int p = 0; p < 4; ++p) {
        int kk = r0 + p * 16;
        float4 d = *(const float4*)(src + (size_t)(kt * 64 + kk) * 1024 + nb * 64 + c4);
        tile[kk][c4+0]=d.x; tile[kk][c4+1]=d.y; tile[kk][c4+2]=d.z; tile[kk][c4+3]=d.w;
    }
    __syncthreads();
    #pragma unroll
    for (int i = 0; i < 2; ++i) {
        int f = t + 256 * i;                    // 0..511
        int chalf = f >> 8;
        int ksl   = (f >> 7) & 1;
        int nt    = (f >> 6) & 1;
        int gv    = (f >> 4) & 3;
        int l15v  = f & 15;
        int n_local = chalf * 32 + 8 * (l15v >> 2) + 4 * nt + (l15v & 3);
        int k_local = ksl * 32 + gv * 8;
        int c  = nb * 2 + chalf;
        int ks = kt * 2 + ksl;
        unsigned short tmp[8];
        #pragma unroll
        for (int e = 0; e < 8; ++e) tmp[e] = f2bf(tile[k_local + e][n_local]);
        size_t off = (size_t)(c * 2 + nt) * 4096 + (size_t)(ks * 512)
                   + (gv * 16 + l15v) * 8;
        *(bf16x8*)(dst + off) = *(const bf16x8*)tmp;
    }
}

// prep_w2: NOW in 8 KB HALF-PANELS of 8 col-tiles: half h = n>>3 of chunk c at
// offset (c*2+h)*4096, span (n&7)*512. Frag element mapping unchanged.
__global__ __launch_bounds__(256) void prep_w2(const float* __restrict__ src,
                                               unsigned short* __restrict__ dst)
{
    __shared__ float tile[64][65];              // [k_local][c_local]
    const int ob = blockIdx.x, kb = blockIdx.y;
    const int t = threadIdx.x;
    const int r0 = t >> 4, c4 = (t & 15) * 4;
    #pragma unroll
    for (int p = 0; p < 4; ++p) {
        int kk = r0 + p * 16;
        float4 d = *(const float4*)(src + (size_t)(kb * 64 + kk) * 256 + ob * 64 + c4);
        tile[kk][c4+0]=d.x; tile[kk][c4+1]=d.y; tile[kk][c4+2]=d.z; tile[kk][c4+3]=d.w;
    }
    __syncthreads();
    #pragma unroll
    for (int i = 0; i < 2; ++i) {
        int f = t + 256 * i;
        int ksl = f >> 8;
        int tq  = (f >> 6) & 3;
        int gv  = (f >> 4) & 3;
        int l15v = f & 15;
        int c_local = tq * 16 + l15v;
        int k_local = ksl * 32 + gv * 8;
        int c = kb * 2 + ksl;
        // global col-tile n = ob*4 + tq; half = n>>3 = ob>>1; span = n&7
        size_t off = (size_t)(c * 2 + (ob >> 1)) * 4096
                   + (size_t)((((ob & 1) * 4 + tq)) * 512)
                   + (gv * 16 + l15v) * 8;
        unsigned short tmp[8];
        #pragma unroll
        for (int e = 0; e < 8; ++e) tmp[e] = f2bf(tile[k_local + e][c_local]);
        *(bf16x8*)(dst + off) = *(const bf16x8*)tmp;
    }
}

// ---------------------------------------------------------------------------
// Fused MLP v13: wave-PAIR decomposition. Pair p owns 16 rows; wave nt of the
// pair computes hidden-half nt (8 h-MFMAs, 4 GELUs) and out-column-half nt
// (8 out-MFMAs, oacc[8]). aH halves exchanged via 8B/lane LDS at the existing
// B2 barrier. LDS 40 KB/block -> 4 blocks/CU, grid 1024 -> up to 32 waves/CU.
// Schedule (2 barriers/chunk, every DMA issue->drain spans exactly 1 barrier):
//   B1 | issue w2 halves(c) | h-MFMA(w1c[nt]) GELU Ex-write |
//   B2 | issue w1 subpanels(c+1) | Ex-read -> aH | out-MFMA(w2c[nt])
// ---------------------------------------------------------------------------
__global__ __launch_bounds__(512, 5) void mlp_fused(
    const float* __restrict__ xin, float* __restrict__ xio,
    const unsigned short* __restrict__ wt1, const float* __restrict__ b1,
    const unsigned short* __restrict__ wt2, const float* __restrict__ b2)
{
    __shared__ unsigned short w1c[2][4096];     // slot nt = sub-panel 2c+nt
    __shared__ unsigned short w2c[2][4096];     // slot h  = col-half h of chunk c
    __shared__ float b1s[1024];
    __shared__ unsigned short Ex[4][2][256];    // [pair][nt][lane*4]

    const int tid  = threadIdx.x;
    const int lane = tid & 63;
    const int l15  = lane & 15;
    const int g    = lane >> 4;
    const int wid  = tid >> 6;                  // 0..7
    const int p    = wid >> 1;                  // pair 0..3
    const int nt   = wid & 1;                   // half index
    const int fb   = (g * 16 + l15) * 8;

    const size_t rowbase = (size_t)blockIdx.x * 64;

    // stage one 8 KB panel: exactly one 16B DMA per thread, linear dest
    auto stage8k = [&](const unsigned short* gbase, unsigned short* lbase) {
        load_lds16(gbase + tid * 8, lbase + wid * 512);
    };

    // prologue: w1 sub-panels 0,1
    stage8k(wt1,        &w1c[0][0]);
    stage8k(wt1 + 4096, &w1c[1][0]);

    b1s[tid]       = b1[tid];
    b1s[tid + 512] = b1[tid + 512];

    // x fragments for the pair's 16 rows (both waves load the same rows)
    bf16x8 xf[8];
    {
        const float* xr = xin + (rowbase + p * 16 + l15) * 256;
        #pragma unroll
        for (int ks = 0; ks < 8; ++ks) {
            float4 a0 = *(const float4*)(xr + ks * 32 + g * 8);
            float4 a1 = *(const float4*)(xr + ks * 32 + g * 8 + 4);
            xf[ks] = pack8(a0, a1);
        }
    }

    f32x4 oacc[8] = {};   // 16 rows x 128 cols (own column half)

    for (int c = 0; c < 32; ++c) {
        __syncthreads();   // B1: drains w1(2c,2c+1); w2 slots free (out(c-1) done)

        stage8k(wt2 + (size_t)(2 * c + 0) * 4096, &w2c[0][0]);
        stage8k(wt2 + (size_t)(2 * c + 1) * 4096, &w2c[1][0]);

        // ---- h-phase: wave nt computes hidden-half nt for the pair's rows ----
        f32x4 hacc = {0.f, 0.f, 0.f, 0.f};
        #pragma unroll
        for (int ks = 0; ks < 8; ++ks) {
            bf16x8 wf = *(const bf16x8*)&w1c[nt][ks * 512 + fb];
            hacc = mfma_bf16(wf, xf[ks], hacc);
        }

        // bias + GELU (4 values) -> own aH half; publish to Ex
        float4 bb = *(const float4*)&b1s[c * 32 + g * 8 + nt * 4];
        us4 own;
        own[0] = f2bf(gelu_erf(hacc[0] + bb.x));
        own[1] = f2bf(gelu_erf(hacc[1] + bb.y));
        own[2] = f2bf(gelu_erf(hacc[2] + bb.z));
        own[3] = f2bf(gelu_erf(hacc[3] + bb.w));
        *(us4*)&Ex[p][nt][lane * 4] = own;

        __syncthreads();   // B2: w2(c) drained; Ex visible; w1 slots free

        if (c < 31) {
            stage8k(wt1 + (size_t)(2 * c + 2) * 4096, &w1c[0][0]);
            stage8k(wt1 + (size_t)(2 * c + 3) * 4096, &w1c[1][0]);
        }

        // assemble full aH (hidden g*8 + 0..7)
        us4 other = *(const us4*)&Ex[p][nt ^ 1][lane * 4];
        bf16x8 aH;
        if (nt == 0) {
            aH[0]=(short)own[0];   aH[1]=(short)own[1];   aH[2]=(short)own[2];   aH[3]=(short)own[3];
            aH[4]=(short)other[0]; aH[5]=(short)other[1]; aH[6]=(short)other[2]; aH[7]=(short)other[3];
        } else {
            aH[0]=(short)other[0]; aH[1]=(short)other[1]; aH[2]=(short)other[2]; aH[3]=(short)other[3];
            aH[4]=(short)own[0];   aH[5]=(short)own[1];   aH[6]=(short)own[2];   aH[7]=(short)own[3];
        }

        // ---- out-phase: own column half (8 col-tiles) ----
        #pragma unroll
        for (int n = 0; n < 8; ++n) {
            bf16x8 bF = *(const bf16x8*)&w2c[nt][n * 512 + fb];
            oacc[n] = mfma_bf16(aH, bF, oacc[n]);
        }
    }

    // ---- epilogue: out = oacc + b2 + residual (16 rows x own 128 cols) ----
    #pragma unroll
    for (int n = 0; n < 8; ++n) {
        int col = nt * 128 + n * 16 + l15;
        float bias = b2[col];
        #pragma unroll
        for (int r = 0; r < 4; ++r) {
            size_t idx = (rowbase + p * 16 + g * 4 + r) * 256 + col;
            xio[idx] = oacc[n][r] + bias + xio[idx];
        }
    }
}

// ---------------------------------------------------------------------------
extern "C" void kernel_launch(void* const* d_in, const int* in_sizes, int n_in,
                              void* d_out, int out_size, void* d_ws, size_t ws_size,
                              hipStream_t stream)
{
    const float* q    = (const float*)d_in[0];
    const float* k    = (const float*)d_in[1];
    const float* v    = (const float*)d_in[2];
    const float* mask = (const float*)d_in[3];
    const float* w1   = (const float*)d_in[6];
    const float* b1   = (const float*)d_in[7];
    const float* w2   = (const float*)d_in[8];
    const float* b2   = (const float*)d_in[9];

    float* xio = (float*)d_out;

    unsigned short* wt1 = (unsigned short*)d_ws;                 // 64 sub-panels x 8 KB
    unsigned short* wt2 = wt1 + (size_t)1024 * 256;              // 64 half-panels x 8 KB

    prep_w1<<<dim3(4, 16), 256, 0, stream>>>(w1, wt1);
    prep_w2<<<dim3(4, 16), 256, 0, stream>>>(w2, wt2);

    attn_kernel<<<8192, 256, 0, stream>>>(q, k, v, mask, xio);

    mlp_fused<<<1024, 512, 0, stream>>>(xio, xio, wt1, b1, wt2, b2);
}

// Round 15
// 163.694 us; speedup vs baseline: 1.1073x; 1.1073x over previous
//
#include <hip/hip_runtime.h>
#include <hip/hip_bf16.h>
#include <cstdint>
#include <cstddef>

typedef __attribute__((ext_vector_type(8))) short bf16x8;    // 8 bf16 in 4 VGPRs
typedef __attribute__((ext_vector_type(4))) float f32x4;
typedef __attribute__((ext_vector_type(16))) float f32x16;

// Native bf16 convert (RNE).
static __device__ __forceinline__ unsigned short f2bf(float f) {
    __hip_bfloat16 h = __float2bfloat16(f);
    return *reinterpret_cast<unsigned short*>(&h);
}

static __device__ __forceinline__ f32x4 mfma_bf16(bf16x8 a, bf16x8 b, f32x4 c) {
    return __builtin_amdgcn_mfma_f32_16x16x32_bf16(a, b, c, 0, 0, 0);
}
static __device__ __forceinline__ f32x16 mfma32(bf16x8 a, bf16x8 b, f32x16 c) {
    return __builtin_amdgcn_mfma_f32_32x32x16_bf16(a, b, c, 0, 0, 0);
}

static __device__ __forceinline__ bf16x8 pack8(float4 a, float4 b) {
    bf16x8 f;
    f[0]=(short)f2bf(a.x); f[1]=(short)f2bf(a.y); f[2]=(short)f2bf(a.z); f[3]=(short)f2bf(a.w);
    f[4]=(short)f2bf(b.x); f[5]=(short)f2bf(b.y); f[6]=(short)f2bf(b.z); f[7]=(short)f2bf(b.w);
    return f;
}

// Branchless exact-erf GELU (A&S 7.1.26, |erf err| < 1.5e-7).
static __device__ __forceinline__ float gelu_erf(float v) {
    float s = v * 0.70710678118654752f;
    float a = fabsf(s);
    float t = __builtin_amdgcn_rcpf(1.0f + 0.3275911f * a);
    float poly = ((((1.061405429f * t - 1.453152027f) * t + 1.421413741f) * t
                   - 0.284496736f) * t + 0.254829592f) * t;
    float e = 1.0f - poly * __expf(-a * a);
    float erfv = copysignf(e, s);
    return 0.5f * v * (1.0f + erfv);
}

// async 16B global -> LDS (linear dest: wave-uniform base + lane*16)
static __device__ __forceinline__ void load_lds16(const unsigned short* g, unsigned short* l) {
    __builtin_amdgcn_global_load_lds(
        (const __attribute__((address_space(1))) unsigned int*)g,
        (__attribute__((address_space(3))) unsigned int*)l, 16, 0, 0);
}

// ---------------------------------------------------------------------------
// Attention (at its HBM floor ~45us): one block per (window, head).
// ---------------------------------------------------------------------------
__global__ __launch_bounds__(256) void attn_kernel(
    const float* __restrict__ q, const float* __restrict__ k,
    const float* __restrict__ v, const float* __restrict__ mask,
    float* __restrict__ xout)
{
    __shared__ unsigned short Qs[64][40];
    __shared__ unsigned short Ks[64][40];
    __shared__ unsigned short Vt[32][72];
    __shared__ unsigned short Ps[64][72];

    const int tid  = threadIdx.x;
    const int b    = blockIdx.x >> 3;
    const int h    = blockIdx.x & 7;
    const int lane = tid & 63;
    const int l15  = lane & 15;
    const int g    = lane >> 4;
    const int w    = tid >> 6;

    {
        int row = tid >> 2;
        int seg = tid & 3;
        size_t base = ((size_t)(b * 64 + row)) * 256 + h * 32 + seg * 8;

        float4 a0 = *(const float4*)(q + base);
        float4 a1 = *(const float4*)(q + base + 4);
        unsigned short* p = &Qs[row][seg * 8];
        p[0]=f2bf(a0.x); p[1]=f2bf(a0.y); p[2]=f2bf(a0.z); p[3]=f2bf(a0.w);
        p[4]=f2bf(a1.x); p[5]=f2bf(a1.y); p[6]=f2bf(a1.z); p[7]=f2bf(a1.w);

        a0 = *(const float4*)(k + base);
        a1 = *(const float4*)(k + base + 4);
        p = &Ks[row][seg * 8];
        p[0]=f2bf(a0.x); p[1]=f2bf(a0.y); p[2]=f2bf(a0.z); p[3]=f2bf(a0.w);
        p[4]=f2bf(a1.x); p[5]=f2bf(a1.y); p[6]=f2bf(a1.z); p[7]=f2bf(a1.w);

        a0 = *(const float4*)(v + base);
        a1 = *(const float4*)(v + base + 4);
        int c = seg * 8;
        Vt[c + 0][row] = f2bf(a0.x);
        Vt[c + 1][row] = f2bf(a0.y);
        Vt[c + 2][row] = f2bf(a0.z);
        Vt[c + 3][row] = f2bf(a0.w);
        Vt[c + 4][row] = f2bf(a1.x);
        Vt[c + 5][row] = f2bf(a1.y);
        Vt[c + 6][row] = f2bf(a1.z);
        Vt[c + 7][row] = f2bf(a1.w);
    }
    __syncthreads();

    f32x4 s[4];
    {
        bf16x8 aQ = *(const bf16x8*)&Qs[w * 16 + l15][g * 8];
        #pragma unroll
        for (int ct = 0; ct < 4; ++ct) {
            bf16x8 bK = *(const bf16x8*)&Ks[ct * 16 + l15][g * 8];
            f32x4 z = {0.f, 0.f, 0.f, 0.f};
            s[ct] = mfma_bf16(aQ, bK, z);
        }
    }

    const float* mbase = mask + (size_t)(b & 63) * 4096;
    const float INV = 0.17677669529663688f;
    float rsum[4];
    #pragma unroll
    for (int r = 0; r < 4; ++r) {
        int row = w * 16 + g * 4 + r;
        float pr[4];
        #pragma unroll
        for (int ct = 0; ct < 4; ++ct)
            pr[ct] = (s[ct][r] + mbase[row * 64 + ct * 16 + l15]) * INV;
        float m = fmaxf(fmaxf(pr[0], pr[1]), fmaxf(pr[2], pr[3]));
        #pragma unroll
        for (int off = 1; off < 16; off <<= 1)
            m = fmaxf(m, __shfl_xor(m, off));
        float sum = 0.f;
        #pragma unroll
        for (int ct = 0; ct < 4; ++ct) { pr[ct] = __expf(pr[ct] - m); sum += pr[ct]; }
        #pragma unroll
        for (int off = 1; off < 16; off <<= 1)
            sum += __shfl_xor(sum, off);
        rsum[r] = sum;
        #pragma unroll
        for (int ct = 0; ct < 4; ++ct)
            Ps[row][ct * 16 + l15] = f2bf(pr[ct]);
    }

    f32x4 o[2] = {};
    #pragma unroll
    for (int ks = 0; ks < 2; ++ks) {
        bf16x8 pa = *(const bf16x8*)&Ps[w * 16 + l15][ks * 32 + g * 8];
        #pragma unroll
        for (int n = 0; n < 2; ++n) {
            bf16x8 vb = *(const bf16x8*)&Vt[n * 16 + l15][ks * 32 + g * 8];
            o[n] = mfma_bf16(pa, vb, o[n]);
        }
    }

    #pragma unroll
    for (int n = 0; n < 2; ++n) {
        #pragma unroll
        for (int r = 0; r < 4; ++r) {
            int row = w * 16 + g * 4 + r;
            xout[((size_t)(b * 64 + row)) * 256 + h * 32 + n * 16 + l15] =
                o[n][r] / rsum[r];
        }
    }
}

// ---------------------------------------------------------------------------
// sigma(a): hidden value placed at 32x32-MFMA A-row position a so that the
// h-MFMA acc regs deliver hidden = (r>>3)*16 + hi*8 + (r&7) — i.e. regs 0..7
// and 8..15 ARE the two out-MFMA A-fragments after GELU.
// ---------------------------------------------------------------------------
static __device__ __forceinline__ int sigma32(int a) {
    return ((a >> 4) & 1) * 16 + ((a >> 2) & 1) * 8 + ((a >> 3) & 1) * 4 + (a & 3);
}

// prep_w1: w1 fp32 [256][1024] -> chunk c (hidden c*32..+31), 16 spans ks of
// 512 shorts; span ks lane l elem e = w1[ks*16 + (l>>5)*8 + e][c*32 + sigma(l&31)].
// grid 32 x 256 thr.
__global__ __launch_bounds__(256) void prep_w1(const float* __restrict__ src,
                                               unsigned short* __restrict__ dst)
{
    const int c = blockIdx.x;
    const int t = threadIdx.x;
    #pragma unroll
    for (int i = 0; i < 4; ++i) {
        int idx = i * 256 + t;              // 0..1023
        int ks  = idx >> 6;
        int l   = idx & 63;
        int l31 = l & 31, hi = l >> 5;
        int n   = c * 32 + sigma32(l31);
        unsigned short tmp[8];
        #pragma unroll
        for (int e = 0; e < 8; ++e)
            tmp[e] = f2bf(src[(size_t)(ks * 16 + hi * 8 + e) * 1024 + n]);
        *(bf16x8*)(dst + (size_t)c * 8192 + ks * 512 + l * 8) = *(const bf16x8*)tmp;
    }
}

// prep_w2: w2 fp32 [1024][256] -> chunk c, span (n*2+j): lane l elem e =
// w2[c*32 + j*16 + (l>>5)*8 + e][n*32 + (l&31)].  grid 32 x 256 thr.
__global__ __launch_bounds__(256) void prep_w2(const float* __restrict__ src,
                                               unsigned short* __restrict__ dst)
{
    const int c = blockIdx.x;
    const int t = threadIdx.x;
    #pragma unroll
    for (int i = 0; i < 4; ++i) {
        int idx  = i * 256 + t;
        int span = idx >> 6;                // 0..15
        int l    = idx & 63;
        int n    = span >> 1;
        int j    = span & 1;
        int l31  = l & 31, hi = l >> 5;
        unsigned short tmp[8];
        #pragma unroll
        for (int e = 0; e < 8; ++e)
            tmp[e] = f2bf(src[(size_t)(c * 32 + j * 16 + hi * 8 + e) * 256 + n * 32 + l31]);
        *(bf16x8*)(dst + (size_t)c * 8192 + span * 512 + l * 8) = *(const bf16x8*)tmp;
    }
}

// ---------------------------------------------------------------------------
// Fused MLP v14: 32x32x16 MFMA — halves LDS bytes/FLOP and MFMA issue count.
// 256 thr = 4 waves, wave owns 32 rows (block 128 rows, grid 512, 2 blk/CU).
// Per chunk (32 hidden): h = 16 chained mfma32 (1 w1 read each); GELU in regs
// (sigma layout makes acc regs the out A-frags); out = 8 col-tiles x 2 mfma32
// (1 w2 read each). One barrier per chunk; weights DMA'd double-buffered.
// ---------------------------------------------------------------------------
__global__ __launch_bounds__(256, 2) void mlp_fused(
    const float* __restrict__ xin, float* __restrict__ xio,
    const unsigned short* __restrict__ wt1, const float* __restrict__ b1,
    const unsigned short* __restrict__ wt2, const float* __restrict__ b2)
{
    __shared__ unsigned short w1c[2][8192];     // 16 KB per buf
    __shared__ unsigned short w2c[2][8192];
    __shared__ float b1s[1024];

    const int tid  = threadIdx.x;
    const int lane = tid & 63;
    const int l31  = lane & 31;
    const int hi   = lane >> 5;
    const int wid  = tid >> 6;                  // 0..3
    const int fb   = lane * 8;                  // frag offset within 512-short span

    const size_t rowbase = (size_t)blockIdx.x * 128 + wid * 32;

    auto stage = [&](const unsigned short* gbase, unsigned short* lbase) {
        #pragma unroll
        for (int i = 0; i < 4; ++i) {
            load_lds16(gbase + (i * 256 + tid) * 8,
                       lbase + (i * 256 + wid * 64) * 8);
        }
    };

    stage(wt1, &w1c[0][0]);
    stage(wt2, &w2c[0][0]);

    b1s[tid]       = b1[tid];
    b1s[tid + 256] = b1[tid + 256];
    b1s[tid + 512] = b1[tid + 512];
    b1s[tid + 768] = b1[tid + 768];

    // x fragments: B-operand, lane holds col = own x-row (l31), k = hi*8+e.
    // 16 frags (K=256), 64 VGPR.
    bf16x8 xf[16];
    {
        const float* xr = xin + (rowbase + l31) * 256;
        #pragma unroll
        for (int ks = 0; ks < 16; ++ks) {
            float4 a0 = *(const float4*)(xr + ks * 16 + hi * 8);
            float4 a1 = *(const float4*)(xr + ks * 16 + hi * 8 + 4);
            xf[ks] = pack8(a0, a1);
        }
    }

    f32x16 oacc[8] = {};   // 32 rows x 256 cols (8 col-tiles of 32)

    for (int c = 0; c < 32; ++c) {
        const int cur = c & 1;
        __syncthreads();   // drains chunk-c DMA; frees buf cur^1 for prefetch

        if (c < 31) {
            stage(wt1 + (size_t)(c + 1) * 8192, &w1c[cur ^ 1][0]);
            stage(wt2 + (size_t)(c + 1) * 8192, &w2c[cur ^ 1][0]);
        }

        // ---- h-phase: hacc = w1(sigma-permuted A) x xf over K=256 ----
        f32x16 hacc = {};
        #pragma unroll
        for (int ks = 0; ks < 16; ++ks) {
            bf16x8 wf = *(const bf16x8*)&w1c[cur][ks * 512 + fb];
            hacc = mfma32(wf, xf[ks], hacc);
        }

        // ---- bias + GELU in registers -> two out-MFMA A-frags ----
        // reg r holds hidden (r>>3)*16 + hi*8 + (r&7) for x-row l31.
        const float* bp = &b1s[c * 32 + hi * 8];
        float4 ba0 = *(const float4*)(bp);
        float4 ba1 = *(const float4*)(bp + 4);
        float4 bb0 = *(const float4*)(bp + 16);
        float4 bb1 = *(const float4*)(bp + 20);
        bf16x8 aH0, aH1;
        aH0[0] = (short)f2bf(gelu_erf(hacc[0]  + ba0.x));
        aH0[1] = (short)f2bf(gelu_erf(hacc[1]  + ba0.y));
        aH0[2] = (short)f2bf(gelu_erf(hacc[2]  + ba0.z));
        aH0[3] = (short)f2bf(gelu_erf(hacc[3]  + ba0.w));
        aH0[4] = (short)f2bf(gelu_erf(hacc[4]  + ba1.x));
        aH0[5] = (short)f2bf(gelu_erf(hacc[5]  + ba1.y));
        aH0[6] = (short)f2bf(gelu_erf(hacc[6]  + ba1.z));
        aH0[7] = (short)f2bf(gelu_erf(hacc[7]  + ba1.w));
        aH1[0] = (short)f2bf(gelu_erf(hacc[8]  + bb0.x));
        aH1[1] = (short)f2bf(gelu_erf(hacc[9]  + bb0.y));
        aH1[2] = (short)f2bf(gelu_erf(hacc[10] + bb0.z));
        aH1[3] = (short)f2bf(gelu_erf(hacc[11] + bb0.w));
        aH1[4] = (short)f2bf(gelu_erf(hacc[12] + bb1.x));
        aH1[5] = (short)f2bf(gelu_erf(hacc[13] + bb1.y));
        aH1[6] = (short)f2bf(gelu_erf(hacc[14] + bb1.z));
        aH1[7] = (short)f2bf(gelu_erf(hacc[15] + bb1.w));

        // ---- out-phase: 8 col-tiles x 2 K-halves ----
        #pragma unroll
        for (int n = 0; n < 8; ++n) {
            bf16x8 bF0 = *(const bf16x8*)&w2c[cur][(n * 2 + 0) * 512 + fb];
            bf16x8 bF1 = *(const bf16x8*)&w2c[cur][(n * 2 + 1) * 512 + fb];
            oacc[n] = mfma32(aH0, bF0, oacc[n]);
            oacc[n] = mfma32(aH1, bF1, oacc[n]);
        }
    }

    // ---- epilogue: out = oacc + b2 + residual ----
    // reg r -> row_local = (r&3) + 8*(r>>2) + 4*hi; col = n*32 + l31.
    #pragma unroll
    for (int n = 0; n < 8; ++n) {
        int col = n * 32 + l31;
        float bias = b2[col];
        #pragma unroll
        for (int r = 0; r < 16; ++r) {
            int row_local = (r & 3) + 8 * (r >> 2) + 4 * hi;
            size_t idx = (rowbase + row_local) * 256 + col;
            xio[idx] = oacc[n][r] + bias + xio[idx];
        }
    }
}

// ---------------------------------------------------------------------------
extern "C" void kernel_launch(void* const* d_in, const int* in_sizes, int n_in,
                              void* d_out, int out_size, void* d_ws, size_t ws_size,
                              hipStream_t stream)
{
    const float* q    = (const float*)d_in[0];
    const float* k    = (const float*)d_in[1];
    const float* v    = (const float*)d_in[2];
    const float* mask = (const float*)d_in[3];
    const float* w1   = (const float*)d_in[6];
    const float* b1   = (const float*)d_in[7];
    const float* w2   = (const float*)d_in[8];
    const float* b2   = (const float*)d_in[9];

    float* xio = (float*)d_out;

    unsigned short* wt1 = (unsigned short*)d_ws;                 // 32 chunks x 16 KB
    unsigned short* wt2 = wt1 + (size_t)1024 * 256;

    prep_w1<<<32, 256, 0, stream>>>(w1, wt1);
    prep_w2<<<32, 256, 0, stream>>>(w2, wt2);

    attn_kernel<<<8192, 256, 0, stream>>>(q, k, v, mask, xio);

    mlp_fused<<<512, 256, 0, stream>>>(xio, xio, wt1, b1, wt2, b2);
}

// Round 16
// 163.591 us; speedup vs baseline: 1.1080x; 1.0006x over previous
//
#include <hip/hip_runtime.h>
#include <hip/hip_bf16.h>
#include <cstdint>
#include <cstddef>

typedef __attribute__((ext_vector_type(8))) short bf16x8;    // 8 bf16 in 4 VGPRs
typedef __attribute__((ext_vector_type(4))) float f32x4;
typedef __attribute__((ext_vector_type(16))) float f32x16;

// Native bf16 convert (RNE).
static __device__ __forceinline__ unsigned short f2bf(float f) {
    __hip_bfloat16 h = __float2bfloat16(f);
    return *reinterpret_cast<unsigned short*>(&h);
}

static __device__ __forceinline__ f32x4 mfma_bf16(bf16x8 a, bf16x8 b, f32x4 c) {
    return __builtin_amdgcn_mfma_f32_16x16x32_bf16(a, b, c, 0, 0, 0);
}
static __device__ __forceinline__ f32x16 mfma32(bf16x8 a, bf16x8 b, f32x16 c) {
    return __builtin_amdgcn_mfma_f32_32x32x16_bf16(a, b, c, 0, 0, 0);
}

static __device__ __forceinline__ bf16x8 pack8(float4 a, float4 b) {
    bf16x8 f;
    f[0]=(short)f2bf(a.x); f[1]=(short)f2bf(a.y); f[2]=(short)f2bf(a.z); f[3]=(short)f2bf(a.w);
    f[4]=(short)f2bf(b.x); f[5]=(short)f2bf(b.y); f[6]=(short)f2bf(b.z); f[7]=(short)f2bf(b.w);
    return f;
}

// Branchless GELU via Hastings 3-term erf (|erf err| < 2.5e-5 — exact at bf16 scale).
static __device__ __forceinline__ float gelu_erf(float v) {
    float s = v * 0.70710678118654752f;
    float a = fabsf(s);
    float t = __builtin_amdgcn_rcpf(1.0f + 0.47047f * a);
    float poly = ((0.7478556f * t - 0.0958798f) * t + 0.3480242f) * t;
    float e = 1.0f - poly * __expf(-a * a);
    float erfv = copysignf(e, s);
    return 0.5f * v * (1.0f + erfv);
}

// async 16B global -> LDS (linear dest: wave-uniform base + lane*16)
static __device__ __forceinline__ void load_lds16(const unsigned short* g, unsigned short* l) {
    __builtin_amdgcn_global_load_lds(
        (const __attribute__((address_space(1))) unsigned int*)g,
        (__attribute__((address_space(3))) unsigned int*)l, 16, 0, 0);
}

// ---------------------------------------------------------------------------
// Attention (at its HBM floor ~45us): one block per (window, head).
// ---------------------------------------------------------------------------
__global__ __launch_bounds__(256) void attn_kernel(
    const float* __restrict__ q, const float* __restrict__ k,
    const float* __restrict__ v, const float* __restrict__ mask,
    float* __restrict__ xout)
{
    __shared__ unsigned short Qs[64][40];
    __shared__ unsigned short Ks[64][40];
    __shared__ unsigned short Vt[32][72];
    __shared__ unsigned short Ps[64][72];

    const int tid  = threadIdx.x;
    const int b    = blockIdx.x >> 3;
    const int h    = blockIdx.x & 7;
    const int lane = tid & 63;
    const int l15  = lane & 15;
    const int g    = lane >> 4;
    const int w    = tid >> 6;

    {
        int row = tid >> 2;
        int seg = tid & 3;
        size_t base = ((size_t)(b * 64 + row)) * 256 + h * 32 + seg * 8;

        float4 a0 = *(const float4*)(q + base);
        float4 a1 = *(const float4*)(q + base + 4);
        unsigned short* p = &Qs[row][seg * 8];
        p[0]=f2bf(a0.x); p[1]=f2bf(a0.y); p[2]=f2bf(a0.z); p[3]=f2bf(a0.w);
        p[4]=f2bf(a1.x); p[5]=f2bf(a1.y); p[6]=f2bf(a1.z); p[7]=f2bf(a1.w);

        a0 = *(const float4*)(k + base);
        a1 = *(const float4*)(k + base + 4);
        p = &Ks[row][seg * 8];
        p[0]=f2bf(a0.x); p[1]=f2bf(a0.y); p[2]=f2bf(a0.z); p[3]=f2bf(a0.w);
        p[4]=f2bf(a1.x); p[5]=f2bf(a1.y); p[6]=f2bf(a1.z); p[7]=f2bf(a1.w);

        a0 = *(const float4*)(v + base);
        a1 = *(const float4*)(v + base + 4);
        int c = seg * 8;
        Vt[c + 0][row] = f2bf(a0.x);
        Vt[c + 1][row] = f2bf(a0.y);
        Vt[c + 2][row] = f2bf(a0.z);
        Vt[c + 3][row] = f2bf(a0.w);
        Vt[c + 4][row] = f2bf(a1.x);
        Vt[c + 5][row] = f2bf(a1.y);
        Vt[c + 6][row] = f2bf(a1.z);
        Vt[c + 7][row] = f2bf(a1.w);
    }
    __syncthreads();

    f32x4 s[4];
    {
        bf16x8 aQ = *(const bf16x8*)&Qs[w * 16 + l15][g * 8];
        #pragma unroll
        for (int ct = 0; ct < 4; ++ct) {
            bf16x8 bK = *(const bf16x8*)&Ks[ct * 16 + l15][g * 8];
            f32x4 z = {0.f, 0.f, 0.f, 0.f};
            s[ct] = mfma_bf16(aQ, bK, z);
        }
    }

    const float* mbase = mask + (size_t)(b & 63) * 4096;
    const float INV = 0.17677669529663688f;
    float rsum[4];
    #pragma unroll
    for (int r = 0; r < 4; ++r) {
        int row = w * 16 + g * 4 + r;
        float pr[4];
        #pragma unroll
        for (int ct = 0; ct < 4; ++ct)
            pr[ct] = (s[ct][r] + mbase[row * 64 + ct * 16 + l15]) * INV;
        float m = fmaxf(fmaxf(pr[0], pr[1]), fmaxf(pr[2], pr[3]));
        #pragma unroll
        for (int off = 1; off < 16; off <<= 1)
            m = fmaxf(m, __shfl_xor(m, off));
        float sum = 0.f;
        #pragma unroll
        for (int ct = 0; ct < 4; ++ct) { pr[ct] = __expf(pr[ct] - m); sum += pr[ct]; }
        #pragma unroll
        for (int off = 1; off < 16; off <<= 1)
            sum += __shfl_xor(sum, off);
        rsum[r] = sum;
        #pragma unroll
        for (int ct = 0; ct < 4; ++ct)
            Ps[row][ct * 16 + l15] = f2bf(pr[ct]);
    }

    f32x4 o[2] = {};
    #pragma unroll
    for (int ks = 0; ks < 2; ++ks) {
        bf16x8 pa = *(const bf16x8*)&Ps[w * 16 + l15][ks * 32 + g * 8];
        #pragma unroll
        for (int n = 0; n < 2; ++n) {
            bf16x8 vb = *(const bf16x8*)&Vt[n * 16 + l15][ks * 32 + g * 8];
            o[n] = mfma_bf16(pa, vb, o[n]);
        }
    }

    #pragma unroll
    for (int n = 0; n < 2; ++n) {
        #pragma unroll
        for (int r = 0; r < 4; ++r) {
            int row = w * 16 + g * 4 + r;
            xout[((size_t)(b * 64 + row)) * 256 + h * 32 + n * 16 + l15] =
                o[n][r] / rsum[r];
        }
    }
}

// ---------------------------------------------------------------------------
// sigma(a): hidden value placed at 32x32-MFMA A-row position a so that the
// h-MFMA acc regs deliver hidden = (r>>3)*16 + hi*8 + (r&7).
// ---------------------------------------------------------------------------
static __device__ __forceinline__ int sigma32(int a) {
    return ((a >> 4) & 1) * 16 + ((a >> 2) & 1) * 8 + ((a >> 3) & 1) * 4 + (a & 3);
}

// prep_w1 (unchanged from r15): chunk c, 16 spans ks of 512 shorts.
__global__ __launch_bounds__(256) void prep_w1(const float* __restrict__ src,
                                               unsigned short* __restrict__ dst)
{
    const int c = blockIdx.x;
    const int t = threadIdx.x;
    #pragma unroll
    for (int i = 0; i < 4; ++i) {
        int idx = i * 256 + t;              // 0..1023
        int ks  = idx >> 6;
        int l   = idx & 63;
        int l31 = l & 31, hi = l >> 5;
        int n   = c * 32 + sigma32(l31);
        unsigned short tmp[8];
        #pragma unroll
        for (int e = 0; e < 8; ++e)
            tmp[e] = f2bf(src[(size_t)(ks * 16 + hi * 8 + e) * 1024 + n]);
        *(bf16x8*)(dst + (size_t)c * 8192 + ks * 512 + l * 8) = *(const bf16x8*)tmp;
    }
}

// prep_w2 (unchanged from r15)
__global__ __launch_bounds__(256) void prep_w2(const float* __restrict__ src,
                                               unsigned short* __restrict__ dst)
{
    const int c = blockIdx.x;
    const int t = threadIdx.x;
    #pragma unroll
    for (int i = 0; i < 4; ++i) {
        int idx  = i * 256 + t;
        int span = idx >> 6;                // 0..15
        int l    = idx & 63;
        int n    = span >> 1;
        int j    = span & 1;
        int l31  = l & 31, hi = l >> 5;
        unsigned short tmp[8];
        #pragma unroll
        for (int e = 0; e < 8; ++e)
            tmp[e] = f2bf(src[(size_t)(c * 32 + j * 16 + hi * 8 + e) * 256 + n * 32 + l31]);
        *(bf16x8*)(dst + (size_t)c * 8192 + span * 512 + l * 8) = *(const bf16x8*)tmp;
    }
}

// ---------------------------------------------------------------------------
// Fused MLP v15: 32x32x16 MFMA, 8 waves x 32 rows (256-row block, grid 256,
// single round, 1 block/CU). Interval = 2 chunks per barrier (16 barriers):
// the interval body holds two independent h->GELU->out sequences, so the
// scheduler interleaves out(2i) MFMAs with h/GELU(2i+1) VALU. hacc is
// bias-initialized (C-in = b1, saves the epilogue adds).
// ---------------------------------------------------------------------------
__global__ __launch_bounds__(512, 2) void mlp_fused(
    const float* __restrict__ xin, float* __restrict__ xio,
    const unsigned short* __restrict__ wt1, const float* __restrict__ b1,
    const unsigned short* __restrict__ wt2, const float* __restrict__ b2)
{
    __shared__ unsigned short w1c[2][16384];    // 32 KB per buf = 2 chunks
    __shared__ unsigned short w2c[2][16384];
    __shared__ float b1s[1024];

    const int tid  = threadIdx.x;
    const int lane = tid & 63;
    const int l31  = lane & 31;
    const int hi   = lane >> 5;
    const int wid  = tid >> 6;                  // 0..7
    const int fb   = lane * 8;                  // frag offset within 512-short span

    const size_t rowbase = (size_t)blockIdx.x * 256 + wid * 32;

    // stage one 32 KB interval-panel: 4 x 16B per thread, linear dest
    auto stage = [&](const unsigned short* gbase, unsigned short* lbase) {
        #pragma unroll
        for (int i = 0; i < 4; ++i) {
            load_lds16(gbase + (i * 512 + tid) * 8,
                       lbase + (i * 512 + wid * 64) * 8);
        }
    };

    stage(wt1, &w1c[0][0]);
    stage(wt2, &w2c[0][0]);

    b1s[tid]       = b1[tid];
    b1s[tid + 512] = b1[tid + 512];

    // x fragments: B-operand, lane = own x-row (l31), k = hi*8+e. 64 VGPR.
    bf16x8 xf[16];
    {
        const float* xr = xin + (rowbase + l31) * 256;
        #pragma unroll
        for (int ks = 0; ks < 16; ++ks) {
            float4 a0 = *(const float4*)(xr + ks * 16 + hi * 8);
            float4 a1 = *(const float4*)(xr + ks * 16 + hi * 8 + 4);
            xf[ks] = pack8(a0, a1);
        }
    }

    f32x16 oacc[8] = {};   // 32 rows x 256 cols (8 col-tiles of 32)

    // bias-init helper: reg r holds hidden (r>>3)*16 + hi*8 + (r&7) of chunk c
    auto bias_init = [&](int c) -> f32x16 {
        const float* bp = &b1s[c * 32 + hi * 8];
        float4 b0 = *(const float4*)(bp);
        float4 b1v = *(const float4*)(bp + 4);
        float4 b2v = *(const float4*)(bp + 16);
        float4 b3 = *(const float4*)(bp + 20);
        f32x16 h;
        h[0]=b0.x;  h[1]=b0.y;  h[2]=b0.z;  h[3]=b0.w;
        h[4]=b1v.x; h[5]=b1v.y; h[6]=b1v.z; h[7]=b1v.w;
        h[8]=b2v.x; h[9]=b2v.y; h[10]=b2v.z; h[11]=b2v.w;
        h[12]=b3.x; h[13]=b3.y; h[14]=b3.z; h[15]=b3.w;
        return h;
    };

    for (int i = 0; i < 16; ++i) {
        const int cur = i & 1;
        __syncthreads();   // drains interval-i DMA; frees buf cur^1

        if (i < 15) {
            stage(wt1 + (size_t)(i + 1) * 16384, &w1c[cur ^ 1][0]);
            stage(wt2 + (size_t)(i + 1) * 16384, &w2c[cur ^ 1][0]);
        }

        // ---- chunk A = 2i: h-MFMA (bias-seeded) ----
        f32x16 haccA = bias_init(2 * i);
        #pragma unroll
        for (int ks = 0; ks < 16; ++ks) {
            bf16x8 wf = *(const bf16x8*)&w1c[cur][ks * 512 + fb];
            haccA = mfma32(wf, xf[ks], haccA);
        }
        bf16x8 aH0, aH1;
        #pragma unroll
        for (int e = 0; e < 8; ++e) {
            aH0[e] = (short)f2bf(gelu_erf(haccA[e]));
            aH1[e] = (short)f2bf(gelu_erf(haccA[e + 8]));
        }

        // ---- chunk B = 2i+1: h-MFMA (independent of out(A) below) ----
        f32x16 haccB = bias_init(2 * i + 1);
        #pragma unroll
        for (int ks = 0; ks < 16; ++ks) {
            bf16x8 wf = *(const bf16x8*)&w1c[cur][(16 + ks) * 512 + fb];
            haccB = mfma32(wf, xf[ks], haccB);
        }
        bf16x8 cH0, cH1;
        #pragma unroll
        for (int e = 0; e < 8; ++e) {
            cH0[e] = (short)f2bf(gelu_erf(haccB[e]));
            cH1[e] = (short)f2bf(gelu_erf(haccB[e + 8]));
        }

        // ---- out(A): 8 col-tiles x 2 K-halves (interleavable with above) ----
        #pragma unroll
        for (int n = 0; n < 8; ++n) {
            bf16x8 bF0 = *(const bf16x8*)&w2c[cur][(n * 2 + 0) * 512 + fb];
            bf16x8 bF1 = *(const bf16x8*)&w2c[cur][(n * 2 + 1) * 512 + fb];
            oacc[n] = mfma32(aH0, bF0, oacc[n]);
            oacc[n] = mfma32(aH1, bF1, oacc[n]);
        }
        // ---- out(B) ----
        #pragma unroll
        for (int n = 0; n < 8; ++n) {
            bf16x8 bF0 = *(const bf16x8*)&w2c[cur][(16 + n * 2 + 0) * 512 + fb];
            bf16x8 bF1 = *(const bf16x8*)&w2c[cur][(16 + n * 2 + 1) * 512 + fb];
            oacc[n] = mfma32(cH0, bF0, oacc[n]);
            oacc[n] = mfma32(cH1, bF1, oacc[n]);
        }
    }

    // ---- epilogue: out = oacc + b2 + residual ----
    // reg r -> row_local = (r&3) + 8*(r>>2) + 4*hi; col = n*32 + l31.
    #pragma unroll
    for (int n = 0; n < 8; ++n) {
        int col = n * 32 + l31;
        float bias = b2[col];
        #pragma unroll
        for (int r = 0; r < 16; ++r) {
            int row_local = (r & 3) + 8 * (r >> 2) + 4 * hi;
            size_t idx = (rowbase + row_local) * 256 + col;
            xio[idx] = oacc[n][r] + bias + xio[idx];
        }
    }
}

// ---------------------------------------------------------------------------
extern "C" void kernel_launch(void* const* d_in, const int* in_sizes, int n_in,
                              void* d_out, int out_size, void* d_ws, size_t ws_size,
                              hipStream_t stream)
{
    const float* q    = (const float*)d_in[0];
    const float* k    = (const float*)d_in[1];
    const float* v    = (const float*)d_in[2];
    const float* mask = (const float*)d_in[3];
    const float* w1   = (const float*)d_in[6];
    const float* b1   = (const float*)d_in[7];
    const float* w2   = (const float*)d_in[8];
    const float* b2   = (const float*)d_in[9];

    float* xio = (float*)d_out;

    unsigned short* wt1 = (unsigned short*)d_ws;                 // 32 chunks x 16 KB
    unsigned short* wt2 = wt1 + (size_t)1024 * 256;

    prep_w1<<<32, 256, 0, stream>>>(w1, wt1);
    prep_w2<<<32, 256, 0, stream>>>(w2, wt2);

    attn_kernel<<<8192, 256, 0, stream>>>(q, k, v, mask, xio);

    mlp_fused<<<256, 512, 0, stream>>>(xio, xio, wt1, b1, wt2, b2);
}

// Round 17
// 158.755 us; speedup vs baseline: 1.1418x; 1.0305x over previous
//
#include <hip/hip_runtime.h>
#include <hip/hip_bf16.h>
#include <cstdint>
#include <cstddef>

typedef __attribute__((ext_vector_type(8))) short bf16x8;    // 8 bf16 in 4 VGPRs
typedef __attribute__((ext_vector_type(4))) float f32x4;
typedef __attribute__((ext_vector_type(16))) float f32x16;

// Native bf16 convert (RNE).
static __device__ __forceinline__ unsigned short f2bf(float f) {
    __hip_bfloat16 h = __float2bfloat16(f);
    return *reinterpret_cast<unsigned short*>(&h);
}
static __device__ __forceinline__ float bf2f(unsigned short u) {
    union { unsigned int i; float f; } x; x.i = ((unsigned int)u) << 16;
    return x.f;
}

static __device__ __forceinline__ f32x4 mfma_bf16(bf16x8 a, bf16x8 b, f32x4 c) {
    return __builtin_amdgcn_mfma_f32_16x16x32_bf16(a, b, c, 0, 0, 0);
}
static __device__ __forceinline__ f32x16 mfma32(bf16x8 a, bf16x8 b, f32x16 c) {
    return __builtin_amdgcn_mfma_f32_32x32x16_bf16(a, b, c, 0, 0, 0);
}

static __device__ __forceinline__ bf16x8 pack8(float4 a, float4 b) {
    bf16x8 f;
    f[0]=(short)f2bf(a.x); f[1]=(short)f2bf(a.y); f[2]=(short)f2bf(a.z); f[3]=(short)f2bf(a.w);
    f[4]=(short)f2bf(b.x); f[5]=(short)f2bf(b.y); f[6]=(short)f2bf(b.z); f[7]=(short)f2bf(b.w);
    return f;
}

// Branchless GELU via Hastings 3-term erf (|erf err| < 2.5e-5).
static __device__ __forceinline__ float gelu_erf(float v) {
    float s = v * 0.70710678118654752f;
    float a = fabsf(s);
    float t = __builtin_amdgcn_rcpf(1.0f + 0.47047f * a);
    float poly = ((0.7478556f * t - 0.0958798f) * t + 0.3480242f) * t;
    float e = 1.0f - poly * __expf(-a * a);
    float erfv = copysignf(e, s);
    return 0.5f * v * (1.0f + erfv);
}

// async 16B global -> LDS (linear dest: wave-uniform base + lane*16)
static __device__ __forceinline__ void load_lds16(const unsigned short* g, unsigned short* l) {
    __builtin_amdgcn_global_load_lds(
        (const __attribute__((address_space(1))) unsigned int*)g,
        (__attribute__((address_space(3))) unsigned int*)l, 16, 0, 0);
}

// ---------------------------------------------------------------------------
// Attention: one block per (window, head). Writes bf16 (to ws) or fp32 (d_out).
// ---------------------------------------------------------------------------
template <bool BF16X>
__global__ __launch_bounds__(256) void attn_kernel(
    const float* __restrict__ q, const float* __restrict__ k,
    const float* __restrict__ v, const float* __restrict__ mask,
    float* __restrict__ xo_f, unsigned short* __restrict__ xo_b)
{
    __shared__ unsigned short Qs[64][40];
    __shared__ unsigned short Ks[64][40];
    __shared__ unsigned short Vt[32][72];
    __shared__ unsigned short Ps[64][72];

    const int tid  = threadIdx.x;
    const int b    = blockIdx.x >> 3;
    const int h    = blockIdx.x & 7;
    const int lane = tid & 63;
    const int l15  = lane & 15;
    const int g    = lane >> 4;
    const int w    = tid >> 6;

    {
        int row = tid >> 2;
        int seg = tid & 3;
        size_t base = ((size_t)(b * 64 + row)) * 256 + h * 32 + seg * 8;

        float4 a0 = *(const float4*)(q + base);
        float4 a1 = *(const float4*)(q + base + 4);
        unsigned short* p = &Qs[row][seg * 8];
        p[0]=f2bf(a0.x); p[1]=f2bf(a0.y); p[2]=f2bf(a0.z); p[3]=f2bf(a0.w);
        p[4]=f2bf(a1.x); p[5]=f2bf(a1.y); p[6]=f2bf(a1.z); p[7]=f2bf(a1.w);

        a0 = *(const float4*)(k + base);
        a1 = *(const float4*)(k + base + 4);
        p = &Ks[row][seg * 8];
        p[0]=f2bf(a0.x); p[1]=f2bf(a0.y); p[2]=f2bf(a0.z); p[3]=f2bf(a0.w);
        p[4]=f2bf(a1.x); p[5]=f2bf(a1.y); p[6]=f2bf(a1.z); p[7]=f2bf(a1.w);

        a0 = *(const float4*)(v + base);
        a1 = *(const float4*)(v + base + 4);
        int c = seg * 8;
        Vt[c + 0][row] = f2bf(a0.x);
        Vt[c + 1][row] = f2bf(a0.y);
        Vt[c + 2][row] = f2bf(a0.z);
        Vt[c + 3][row] = f2bf(a0.w);
        Vt[c + 4][row] = f2bf(a1.x);
        Vt[c + 5][row] = f2bf(a1.y);
        Vt[c + 6][row] = f2bf(a1.z);
        Vt[c + 7][row] = f2bf(a1.w);
    }
    __syncthreads();

    f32x4 s[4];
    {
        bf16x8 aQ = *(const bf16x8*)&Qs[w * 16 + l15][g * 8];
        #pragma unroll
        for (int ct = 0; ct < 4; ++ct) {
            bf16x8 bK = *(const bf16x8*)&Ks[ct * 16 + l15][g * 8];
            f32x4 z = {0.f, 0.f, 0.f, 0.f};
            s[ct] = mfma_bf16(aQ, bK, z);
        }
    }

    const float* mbase = mask + (size_t)(b & 63) * 4096;
    const float INV = 0.17677669529663688f;
    float rsum[4];
    #pragma unroll
    for (int r = 0; r < 4; ++r) {
        int row = w * 16 + g * 4 + r;
        float pr[4];
        #pragma unroll
        for (int ct = 0; ct < 4; ++ct)
            pr[ct] = (s[ct][r] + mbase[row * 64 + ct * 16 + l15]) * INV;
        float m = fmaxf(fmaxf(pr[0], pr[1]), fmaxf(pr[2], pr[3]));
        #pragma unroll
        for (int off = 1; off < 16; off <<= 1)
            m = fmaxf(m, __shfl_xor(m, off));
        float sum = 0.f;
        #pragma unroll
        for (int ct = 0; ct < 4; ++ct) { pr[ct] = __expf(pr[ct] - m); sum += pr[ct]; }
        #pragma unroll
        for (int off = 1; off < 16; off <<= 1)
            sum += __shfl_xor(sum, off);
        rsum[r] = sum;
        #pragma unroll
        for (int ct = 0; ct < 4; ++ct)
            Ps[row][ct * 16 + l15] = f2bf(pr[ct]);
    }

    f32x4 o[2] = {};
    #pragma unroll
    for (int ks = 0; ks < 2; ++ks) {
        bf16x8 pa = *(const bf16x8*)&Ps[w * 16 + l15][ks * 32 + g * 8];
        #pragma unroll
        for (int n = 0; n < 2; ++n) {
            bf16x8 vb = *(const bf16x8*)&Vt[n * 16 + l15][ks * 32 + g * 8];
            o[n] = mfma_bf16(pa, vb, o[n]);
        }
    }

    #pragma unroll
    for (int n = 0; n < 2; ++n) {
        #pragma unroll
        for (int r = 0; r < 4; ++r) {
            int row = w * 16 + g * 4 + r;
            size_t idx = ((size_t)(b * 64 + row)) * 256 + h * 32 + n * 16 + l15;
            float val = o[n][r] / rsum[r];
            if (BF16X) xo_b[idx] = f2bf(val);
            else       xo_f[idx] = val;
        }
    }
}

// ---------------------------------------------------------------------------
// sigma(a): hidden value placed at 32x32-MFMA A-row position a so that the
// h-MFMA acc regs deliver hidden = (r>>3)*16 + hi*8 + (r&7).
// ---------------------------------------------------------------------------
static __device__ __forceinline__ int sigma32(int a) {
    return ((a >> 4) & 1) * 16 + ((a >> 2) & 1) * 8 + ((a >> 3) & 1) * 4 + (a & 3);
}

// prep_w1: chunk c, 16 spans ks of 512 shorts (unchanged, proven).
__global__ __launch_bounds__(256) void prep_w1(const float* __restrict__ src,
                                               unsigned short* __restrict__ dst)
{
    const int c = blockIdx.x;
    const int t = threadIdx.x;
    #pragma unroll
    for (int i = 0; i < 4; ++i) {
        int idx = i * 256 + t;              // 0..1023
        int ks  = idx >> 6;
        int l   = idx & 63;
        int l31 = l & 31, hi = l >> 5;
        int n   = c * 32 + sigma32(l31);
        unsigned short tmp[8];
        #pragma unroll
        for (int e = 0; e < 8; ++e)
            tmp[e] = f2bf(src[(size_t)(ks * 16 + hi * 8 + e) * 1024 + n]);
        *(bf16x8*)(dst + (size_t)c * 8192 + ks * 512 + l * 8) = *(const bf16x8*)tmp;
    }
}

// prep_w2 (unchanged, proven)
__global__ __launch_bounds__(256) void prep_w2(const float* __restrict__ src,
                                               unsigned short* __restrict__ dst)
{
    const int c = blockIdx.x;
    const int t = threadIdx.x;
    #pragma unroll
    for (int i = 0; i < 4; ++i) {
        int idx  = i * 256 + t;
        int span = idx >> 6;                // 0..15
        int l    = idx & 63;
        int n    = span >> 1;
        int j    = span & 1;
        int l31  = l & 31, hi = l >> 5;
        unsigned short tmp[8];
        #pragma unroll
        for (int e = 0; e < 8; ++e)
            tmp[e] = f2bf(src[(size_t)(c * 32 + j * 16 + hi * 8 + e) * 256 + n * 32 + l31]);
        *(bf16x8*)(dst + (size_t)c * 8192 + span * 512 + l * 8) = *(const bf16x8*)tmp;
    }
}

// ---------------------------------------------------------------------------
// Fused MLP v16 = v14 launch shape (256 thr, 4 waves x 32 rows, grid 512,
// 2 blocks/CU) + bias-seeded hacc + Hastings GELU + setprio around MFMA
// clusters + optional bf16 x input (xf direct-load, bf16 residual).
// ---------------------------------------------------------------------------
template <bool BF16X>
__global__ __launch_bounds__(256, 2) void mlp_fused(
    const float* __restrict__ xin_f, const unsigned short* __restrict__ xin_b,
    float* __restrict__ out,
    const unsigned short* __restrict__ wt1, const float* __restrict__ b1,
    const unsigned short* __restrict__ wt2, const float* __restrict__ b2)
{
    __shared__ unsigned short w1c[2][8192];     // 16 KB per buf
    __shared__ unsigned short w2c[2][8192];
    __shared__ float b1s[1024];

    const int tid  = threadIdx.x;
    const int lane = tid & 63;
    const int l31  = lane & 31;
    const int hi   = lane >> 5;
    const int wid  = tid >> 6;                  // 0..3
    const int fb   = lane * 8;                  // frag offset within 512-short span

    const size_t rowbase = (size_t)blockIdx.x * 128 + wid * 32;

    auto stage = [&](const unsigned short* gbase, unsigned short* lbase) {
        #pragma unroll
        for (int i = 0; i < 4; ++i) {
            load_lds16(gbase + (i * 256 + tid) * 8,
                       lbase + (i * 256 + wid * 64) * 8);
        }
    };

    stage(wt1, &w1c[0][0]);
    stage(wt2, &w2c[0][0]);

    b1s[tid]       = b1[tid];
    b1s[tid + 256] = b1[tid + 256];
    b1s[tid + 512] = b1[tid + 512];
    b1s[tid + 768] = b1[tid + 768];

    // x fragments: B-operand, lane = own x-row (l31), k = hi*8+e. 64 VGPR.
    bf16x8 xf[16];
    if (BF16X) {
        const unsigned short* xr = xin_b + (rowbase + l31) * 256;
        #pragma unroll
        for (int ks = 0; ks < 16; ++ks)
            xf[ks] = *(const bf16x8*)(xr + ks * 16 + hi * 8);
    } else {
        const float* xr = xin_f + (rowbase + l31) * 256;
        #pragma unroll
        for (int ks = 0; ks < 16; ++ks) {
            float4 a0 = *(const float4*)(xr + ks * 16 + hi * 8);
            float4 a1 = *(const float4*)(xr + ks * 16 + hi * 8 + 4);
            xf[ks] = pack8(a0, a1);
        }
    }

    f32x16 oacc[8] = {};   // 32 rows x 256 cols (8 col-tiles of 32)

    for (int c = 0; c < 32; ++c) {
        const int cur = c & 1;
        __syncthreads();   // drains chunk-c DMA; frees buf cur^1 for prefetch

        if (c < 31) {
            stage(wt1 + (size_t)(c + 1) * 8192, &w1c[cur ^ 1][0]);
            stage(wt2 + (size_t)(c + 1) * 8192, &w2c[cur ^ 1][0]);
        }

        // ---- bias-seeded h accumulator ----
        f32x16 hacc;
        {
            const float* bp = &b1s[c * 32 + hi * 8];
            float4 b0 = *(const float4*)(bp);
            float4 b1v = *(const float4*)(bp + 4);
            float4 b2v = *(const float4*)(bp + 16);
            float4 b3 = *(const float4*)(bp + 20);
            hacc[0]=b0.x;  hacc[1]=b0.y;  hacc[2]=b0.z;  hacc[3]=b0.w;
            hacc[4]=b1v.x; hacc[5]=b1v.y; hacc[6]=b1v.z; hacc[7]=b1v.w;
            hacc[8]=b2v.x; hacc[9]=b2v.y; hacc[10]=b2v.z; hacc[11]=b2v.w;
            hacc[12]=b3.x; hacc[13]=b3.y; hacc[14]=b3.z; hacc[15]=b3.w;
        }

        // ---- h-phase: 16 chained mfma32 over K=256 ----
        __builtin_amdgcn_s_setprio(1);
        #pragma unroll
        for (int ks = 0; ks < 16; ++ks) {
            bf16x8 wf = *(const bf16x8*)&w1c[cur][ks * 512 + fb];
            hacc = mfma32(wf, xf[ks], hacc);
        }
        __builtin_amdgcn_s_setprio(0);

        // ---- GELU in registers -> two out-MFMA A-frags ----
        bf16x8 aH0, aH1;
        #pragma unroll
        for (int e = 0; e < 8; ++e) {
            aH0[e] = (short)f2bf(gelu_erf(hacc[e]));
            aH1[e] = (short)f2bf(gelu_erf(hacc[e + 8]));
        }

        // ---- out-phase: 8 col-tiles x 2 K-halves ----
        __builtin_amdgcn_s_setprio(1);
        #pragma unroll
        for (int n = 0; n < 8; ++n) {
            bf16x8 bF0 = *(const bf16x8*)&w2c[cur][(n * 2 + 0) * 512 + fb];
            bf16x8 bF1 = *(const bf16x8*)&w2c[cur][(n * 2 + 1) * 512 + fb];
            oacc[n] = mfma32(aH0, bF0, oacc[n]);
            oacc[n] = mfma32(aH1, bF1, oacc[n]);
        }
        __builtin_amdgcn_s_setprio(0);
    }

    // ---- epilogue: out = oacc + b2 + residual ----
    // reg r -> row_local = (r&3) + 8*(r>>2) + 4*hi; col = n*32 + l31.
    #pragma unroll
    for (int n = 0; n < 8; ++n) {
        int col = n * 32 + l31;
        float bias = b2[col];
        #pragma unroll
        for (int r = 0; r < 16; ++r) {
            int row_local = (r & 3) + 8 * (r >> 2) + 4 * hi;
            size_t idx = (rowbase + row_local) * 256 + col;
            float resid = BF16X ? bf2f(xin_b[idx]) : xin_f[idx];
            out[idx] = oacc[n][r] + bias + resid;
        }
    }
}

// ---------------------------------------------------------------------------
extern "C" void kernel_launch(void* const* d_in, const int* in_sizes, int n_in,
                              void* d_out, int out_size, void* d_ws, size_t ws_size,
                              hipStream_t stream)
{
    const float* q    = (const float*)d_in[0];
    const float* k    = (const float*)d_in[1];
    const float* v    = (const float*)d_in[2];
    const float* mask = (const float*)d_in[3];
    const float* w1   = (const float*)d_in[6];
    const float* b1   = (const float*)d_in[7];
    const float* w2   = (const float*)d_in[8];
    const float* b2   = (const float*)d_in[9];

    float* out = (float*)d_out;

    unsigned short* wt1 = (unsigned short*)d_ws;                 // 512 KB
    unsigned short* wt2 = wt1 + (size_t)1024 * 256;              // 512 KB
    unsigned short* xbf = wt2 + (size_t)1024 * 256;              // 32 MB (bf16 x)

    const size_t need = (size_t)2 * 1024 * 256 * 2 + (size_t)65536 * 256 * 2;

    prep_w1<<<32, 256, 0, stream>>>(w1, wt1);
    prep_w2<<<32, 256, 0, stream>>>(w2, wt2);

    if (ws_size >= need) {
        attn_kernel<true><<<8192, 256, 0, stream>>>(q, k, v, mask, nullptr, xbf);
        mlp_fused<true><<<512, 256, 0, stream>>>(nullptr, xbf, out, wt1, b1, wt2, b2);
    } else {
        attn_kernel<false><<<8192, 256, 0, stream>>>(q, k, v, mask, out, nullptr);
        mlp_fused<false><<<512, 256, 0, stream>>>(out, nullptr, out, wt1, b1, wt2, b2);
    }
}